// Round 7
// baseline (1389.223 us; speedup 1.0000x reference)
//
#include <hip/hip_runtime.h>
#include <math.h>

constexpr int D = 512;        // embedding dim
constexpr int KCL = 128;      // clusters
constexpr float BETA_C = 5.0f;
constexpr int SPLIT = 128;    // split-K groups for pass B

typedef __attribute__((ext_vector_type(8))) short short8;
typedef __attribute__((ext_vector_type(4))) float f32x4;

typedef const __attribute__((address_space(1))) unsigned int* gptr_t;
typedef __attribute__((address_space(3))) unsigned int* sptr_t;

static __device__ __forceinline__ unsigned short f2bf(float f) {
    unsigned u = __builtin_bit_cast(unsigned, f);
    unsigned r = (u + 0x7FFFu + ((u >> 16) & 1u)) >> 16;
    return (unsigned short)r;
}
static __device__ __forceinline__ float bf2f(unsigned short h) {
    unsigned u = ((unsigned)h) << 16;
    return __builtin_bit_cast(float, u);
}
static __device__ __forceinline__ unsigned pack_split(float v) {
    unsigned short h = f2bf(v);
    float hf = bf2f(h);
    unsigned short lo = f2bf(v - hf);
    return (unsigned)h | ((unsigned)lo << 16);
}

// split 8 f32 -> hi/lo bf16 frags
static __device__ __forceinline__ void split8(float4 a, float4 b, short8& hi, short8& lo) {
    float v[8] = {a.x, a.y, a.z, a.w, b.x, b.y, b.z, b.w};
    union { unsigned short us[8]; short8 s8; } H, L;
    #pragma unroll
    for (int j = 0; j < 8; ++j) {
        unsigned short h = f2bf(v[j]);
        float hf = bf2f(h);
        H.us[j] = h;
        L.us[j] = f2bf(v[j] - hf);
    }
    hi = H.s8; lo = L.s8;
}

// unpack 8 packed u32 (hi | lo<<16) -> hi/lo bf16 frags
static __device__ __forceinline__ void unpack8(uint4 a, uint4 b, short8& hi, short8& lo) {
    union { unsigned u[4]; short8 s8; } H, L;
    H.u[0] = (a.x & 0xFFFFu) | (a.y << 16);
    H.u[1] = (a.z & 0xFFFFu) | (a.w << 16);
    H.u[2] = (b.x & 0xFFFFu) | (b.y << 16);
    H.u[3] = (b.z & 0xFFFFu) | (b.w << 16);
    L.u[0] = (a.x >> 16) | (a.y & 0xFFFF0000u);
    L.u[1] = (a.z >> 16) | (a.w & 0xFFFF0000u);
    L.u[2] = (b.x >> 16) | (b.y & 0xFFFF0000u);
    L.u[3] = (b.z >> 16) | (b.w & 0xFFFF0000u);
    hi = H.s8; lo = L.s8;
}

// ---------------- conv: x -> xT packed limbs [512][npad] + row sumsq partials ----------------
__global__ __launch_bounds__(256) void conv_xT_kernel(const float* __restrict__ x,
        unsigned* __restrict__ xt, float* __restrict__ normp, int n, int npad)
{
    __shared__ float tile[64 * 132];
    const int t = threadIdx.x;
    const int kbase = blockIdx.x * 64;
    const int dbase = blockIdx.y * 128;

    #pragma unroll
    for (int u = 0; u < 8; ++u) {
        int f = t + u * 256;
        int row = f >> 5;
        int c4 = (f & 31) << 2;
        int gk = kbase + row;
        float4 v = make_float4(0.f, 0.f, 0.f, 0.f);
        if (gk < n) v = *reinterpret_cast<const float4*>(x + (size_t)gk * D + dbase + c4);
        *reinterpret_cast<float4*>(&tile[row * 132 + c4]) = v;
    }
    __syncthreads();

    if (t < 64) {
        int gk = kbase + t;
        if (gk < n) {
            float s = 0.f;
            #pragma unroll
            for (int j = 0; j < 128; ++j) {
                float v = tile[t * 132 + ((j + t) & 127)];
                s += v * v;
            }
            normp[(size_t)blockIdx.y * n + gk] = s;
        }
    }

    int dl = t >> 1, kh = t & 1;
    size_t gb = (size_t)(dbase + dl) * npad + kbase + kh * 32;
    #pragma unroll
    for (int q = 0; q < 8; ++q) {
        uint4 o;
        unsigned* op = reinterpret_cast<unsigned*>(&o);
        #pragma unroll
        for (int j = 0; j < 4; ++j) {
            float v = tile[(kh * 32 + q * 4 + j) * 132 + dl];
            op[j] = pack_split(v);
        }
        *reinterpret_cast<uint4*>(xt + gb + q * 4) = o;
    }
}

__global__ __launch_bounds__(256) void norm_fin_kernel(const float* __restrict__ normp,
        float* __restrict__ inv_norm, int n)
{
    int i = blockIdx.x * 256 + threadIdx.x;
    if (i < n)
        inv_norm[i] = 1.0f / sqrtf(normp[i] + normp[(size_t)n + i] +
                                   normp[2 * (size_t)n + i] + normp[3 * (size_t)n + i]);
}

// ---------------- conversion: mu fp32 -> hi/lo bf16 ----------------
__global__ __launch_bounds__(256) void conv_mu_kernel(const float* __restrict__ mu,
        unsigned short* __restrict__ mh, unsigned short* __restrict__ ml)
{
    int i = blockIdx.x * 256 + threadIdx.x;   // * 4 elements
    float4 v = reinterpret_cast<const float4*>(mu)[i];
    ushort4 h, l;
    float hf;
    h.x = f2bf(v.x); hf = bf2f(h.x); l.x = f2bf(v.x - hf);
    h.y = f2bf(v.y); hf = bf2f(h.y); l.y = f2bf(v.y - hf);
    h.z = f2bf(v.z); hf = bf2f(h.z); l.z = f2bf(v.z - hf);
    h.w = f2bf(v.w); hf = bf2f(h.w); l.w = f2bf(v.w - hf);
    reinterpret_cast<ushort4*>(mh)[i] = h;
    reinterpret_cast<ushort4*>(ml)[i] = l;
}

// ---------------- zero pad region of r_t ----------------
__global__ __launch_bounds__(256) void pad_r_kernel(unsigned* __restrict__ rt, int npad, int k0)
{
    int cnt = npad - k0;
    int idx = blockIdx.x * 256 + threadIdx.x;
    if (idx < KCL * cnt) {
        int cl = idx / cnt;
        int k  = idx - cl * cnt;
        rt[(size_t)cl * npad + k0 + k] = 0u;
    }
}

// ---------------- pass A (MFMA): r = softmax(beta * s_i * (x @ mu^T)) ----------------
// FIN=false: writes r_t packed limbs (transposed) + cluster_r atomics.
// FIN=true : writes plain r fp32 row-major.
template<bool FIN>
__global__ __launch_bounds__(256) void passA_mfma_kernel(
    const float* __restrict__ x,
    const unsigned short* __restrict__ mh, const unsigned short* __restrict__ ml,
    const float* __restrict__ inv_norm, float* __restrict__ r_out,
    unsigned* __restrict__ r_tp, float* __restrict__ cluster_r, int n, int npad)
{
    __shared__ union {
        struct { float a[128 * 32]; unsigned short bh[128 * 32]; unsigned short bl[128 * 32]; } c;
        unsigned T[64 * 130];
    } lds;
    __shared__ float part[4 * 128];

    const int t  = threadIdx.x;
    const int w  = t >> 6;
    const int l  = t & 63;
    const int fr = l & 15;
    const int g  = l >> 4;
    const int rowBase = blockIdx.x * 128;

    f32x4 acc[2][8];
    #pragma unroll
    for (int m = 0; m < 2; ++m)
        #pragma unroll
        for (int nn = 0; nn < 8; ++nn) acc[m][nn] = (f32x4){0.f, 0.f, 0.f, 0.f};

    // staging source pointers (A: f32 x with source-preswizzled chunks; B: mu limbs linear)
    const float* pA[4];
    const unsigned short* pBh[2];
    const unsigned short* pBl[2];
    #pragma unroll
    for (int u = 0; u < 4; ++u) {
        int c   = t + u * 256;          // 0..1023
        int row = c >> 3;
        int ch  = c & 7;
        int ga  = min(rowBase + row, n - 1);
        pA[u] = x + (size_t)ga * D + ((ch ^ (row & 7)) << 2);
    }
    #pragma unroll
    for (int u = 0; u < 2; ++u) {
        int c   = t + u * 256;          // 0..511
        int row = c >> 2;
        int ch  = c & 3;
        pBh[u] = mh + row * D + ch * 8;
        pBl[u] = ml + row * D + ch * 8;
    }

    for (int kb = 0; kb < D; kb += 32) {
        #pragma unroll
        for (int u = 0; u < 4; ++u) {
            int c = t + u * 256;
            __builtin_amdgcn_global_load_lds((gptr_t)pA[u], (sptr_t)&lds.c.a[c * 4], 16, 0, 0);
            pA[u] += 32;
        }
        #pragma unroll
        for (int u = 0; u < 2; ++u) {
            int c = t + u * 256;
            __builtin_amdgcn_global_load_lds((gptr_t)pBh[u], (sptr_t)&lds.c.bh[c * 8], 16, 0, 0);
            __builtin_amdgcn_global_load_lds((gptr_t)pBl[u], (sptr_t)&lds.c.bl[c * 8], 16, 0, 0);
            pBh[u] += 32; pBl[u] += 32;
        }
        __syncthreads();

        const int rA0 = w * 32 + fr;
        const int rA1 = rA0 + 16;
        const int msk = fr & 7;
        float4 q0 = *reinterpret_cast<const float4*>(&lds.c.a[rA0 * 32 + (((2 * g)     ^ msk) << 2)]);
        float4 q1 = *reinterpret_cast<const float4*>(&lds.c.a[rA0 * 32 + (((2 * g + 1) ^ msk) << 2)]);
        float4 q2 = *reinterpret_cast<const float4*>(&lds.c.a[rA1 * 32 + (((2 * g)     ^ msk) << 2)]);
        float4 q3 = *reinterpret_cast<const float4*>(&lds.c.a[rA1 * 32 + (((2 * g + 1) ^ msk) << 2)]);
        short8 ah0, al0, ah1, al1;
        split8(q0, q1, ah0, al0);
        split8(q2, q3, ah1, al1);

        const int fb = g * 8;
        #pragma unroll
        for (int nn = 0; nn < 8; ++nn) {
            short8 bh = *reinterpret_cast<const short8*>(&lds.c.bh[(nn * 16 + fr) * 32 + fb]);
            short8 bl = *reinterpret_cast<const short8*>(&lds.c.bl[(nn * 16 + fr) * 32 + fb]);
            acc[0][nn] = __builtin_amdgcn_mfma_f32_16x16x32_bf16(ah0, bh, acc[0][nn], 0, 0, 0);
            acc[1][nn] = __builtin_amdgcn_mfma_f32_16x16x32_bf16(ah1, bh, acc[1][nn], 0, 0, 0);
            acc[0][nn] = __builtin_amdgcn_mfma_f32_16x16x32_bf16(ah0, bl, acc[0][nn], 0, 0, 0);
            acc[1][nn] = __builtin_amdgcn_mfma_f32_16x16x32_bf16(ah1, bl, acc[1][nn], 0, 0, 0);
            acc[0][nn] = __builtin_amdgcn_mfma_f32_16x16x32_bf16(al0, bh, acc[0][nn], 0, 0, 0);
            acc[1][nn] = __builtin_amdgcn_mfma_f32_16x16x32_bf16(al1, bh, acc[1][nn], 0, 0, 0);
        }
        __syncthreads();
    }

    // -------- softmax + output --------
    float csum[8];
    #pragma unroll
    for (int nn = 0; nn < 8; ++nn) csum[nn] = 0.f;

    #pragma unroll
    for (int m = 0; m < 2; ++m) {
        #pragma unroll
        for (int rr = 0; rr < 4; ++rr) {
            int row = rowBase + w * 32 + m * 16 + g * 4 + rr;
            bool valid = row < n;
            float sv = inv_norm[min(row, n - 1)];
            float bs = BETA_C * sv;
            float lg[8];
            float mx = -3.0e38f;
            #pragma unroll
            for (int nn = 0; nn < 8; ++nn) { lg[nn] = bs * acc[m][nn][rr]; mx = fmaxf(mx, lg[nn]); }
            #pragma unroll
            for (int sh = 1; sh < 16; sh <<= 1) mx = fmaxf(mx, __shfl_xor(mx, sh, 64));
            float e[8];
            float sum = 0.f;
            #pragma unroll
            for (int nn = 0; nn < 8; ++nn) { e[nn] = __expf(lg[nn] - mx); sum += e[nn]; }
            #pragma unroll
            for (int sh = 1; sh < 16; sh <<= 1) sum += __shfl_xor(sum, sh, 64);
            float rinv = 1.0f / sum;

            if (FIN) {
                if (valid) {
                    float* ro = r_out + (size_t)row * KCL + fr;
                    #pragma unroll
                    for (int nn = 0; nn < 8; ++nn) ro[nn * 16] = e[nn] * rinv;
                }
            } else {
                int trow = w * 16 + g * 4 + rr;
                #pragma unroll
                for (int nn = 0; nn < 8; ++nn) {
                    unsigned wv = 0u;
                    if (valid) {
                        float rv = e[nn] * rinv;
                        csum[nn] += rv;
                        wv = pack_split(rv * sv);     // r' = r * s_i, packed limbs
                    }
                    lds.T[trow * 130 + nn * 16 + fr] = wv;
                }
            }
        }
        if (!FIN) {
            __syncthreads();
            // coalesced transpose write: 4-lane groups cover 64B contiguous k-runs
            #pragma unroll
            for (int u = 0; u < 2; ++u) {
                int item = t + u * 256;     // 0..511
                int cl = item >> 2;         // 0..127
                int q  = item & 3;          // 0..3  (16B each -> 64B per cl run)
                #pragma unroll
                for (int wg = 0; wg < 4; ++wg) {
                    uint4 v;
                    v.x = lds.T[(wg * 16 + q * 4 + 0) * 130 + cl];
                    v.y = lds.T[(wg * 16 + q * 4 + 1) * 130 + cl];
                    v.z = lds.T[(wg * 16 + q * 4 + 2) * 130 + cl];
                    v.w = lds.T[(wg * 16 + q * 4 + 3) * 130 + cl];
                    *reinterpret_cast<uint4*>(r_tp + (size_t)cl * npad + rowBase + wg * 32 + m * 16 + q * 4) = v;
                }
            }
            __syncthreads();
        }
    }

    if (!FIN) {
        #pragma unroll
        for (int nn = 0; nn < 8; ++nn) {
            csum[nn] += __shfl_xor(csum[nn], 16, 64);
            csum[nn] += __shfl_xor(csum[nn], 32, 64);
        }
        if (l < 16) {
            #pragma unroll
            for (int nn = 0; nn < 8; ++nn) part[w * 128 + nn * 16 + l] = csum[nn];
        }
        __syncthreads();
        if (t < 128) {
            atomicAdd(&cluster_r[t], part[t] + part[128 + t] + part[256 + t] + part[384 + t]);
        }
    }
}

// ---------------- pass B (MFMA): partials[s] = r_t @ xT^T over k-chunk ----------------
__global__ __launch_bounds__(256) void passB_mfma_kernel(
    const unsigned* __restrict__ rt, const unsigned* __restrict__ xt,
    float* __restrict__ partials, int npad, int chunk)
{
    __shared__ __align__(16) unsigned ldsR[128 * 32];
    __shared__ __align__(16) unsigned ldsX[128 * 32];

    const int t  = threadIdx.x;
    const int w  = t >> 6;
    const int l  = t & 63;
    const int fr = l & 15;
    const int g  = l >> 4;
    const int dbase = blockIdx.x * 128;
    const int s  = blockIdx.y;
    const int k0 = s * chunk;

    f32x4 acc[2][8];
    #pragma unroll
    for (int m = 0; m < 2; ++m)
        #pragma unroll
        for (int nn = 0; nn < 8; ++nn) acc[m][nn] = (f32x4){0.f, 0.f, 0.f, 0.f};

    const unsigned* pR[4];
    const unsigned* pX[4];
    #pragma unroll
    for (int u = 0; u < 4; ++u) {
        int c   = t + u * 256;          // 0..1023
        int row = c >> 3;
        int ch  = c & 7;
        int koff = (ch ^ (row & 7)) << 2;     // u32 offset within 32-wide row
        pR[u] = rt + (size_t)row * npad + k0 + koff;
        pX[u] = xt + (size_t)(dbase + row) * npad + k0 + koff;
    }

    for (int kb = 0; kb < chunk; kb += 32) {
        #pragma unroll
        for (int u = 0; u < 4; ++u) {
            int c = t + u * 256;
            __builtin_amdgcn_global_load_lds((gptr_t)pR[u], (sptr_t)&ldsR[c * 4], 16, 0, 0);
            __builtin_amdgcn_global_load_lds((gptr_t)pX[u], (sptr_t)&ldsX[c * 4], 16, 0, 0);
            pR[u] += 32; pX[u] += 32;
        }
        __syncthreads();

        const int msk = fr & 7;
        short8 rh[2], rl[2];
        #pragma unroll
        for (int m = 0; m < 2; ++m) {
            int r0 = w * 32 + m * 16 + fr;
            uint4 a0 = *reinterpret_cast<const uint4*>(&ldsR[r0 * 32 + (((2 * g)     ^ msk) << 2)]);
            uint4 a1 = *reinterpret_cast<const uint4*>(&ldsR[r0 * 32 + (((2 * g + 1) ^ msk) << 2)]);
            unpack8(a0, a1, rh[m], rl[m]);
        }
        #pragma unroll
        for (int nn = 0; nn < 8; ++nn) {
            int rb = nn * 16 + fr;
            uint4 b0 = *reinterpret_cast<const uint4*>(&ldsX[rb * 32 + (((2 * g)     ^ msk) << 2)]);
            uint4 b1 = *reinterpret_cast<const uint4*>(&ldsX[rb * 32 + (((2 * g + 1) ^ msk) << 2)]);
            short8 xh, xl;
            unpack8(b0, b1, xh, xl);
            #pragma unroll
            for (int m = 0; m < 2; ++m) {
                acc[m][nn] = __builtin_amdgcn_mfma_f32_16x16x32_bf16(rh[m], xh, acc[m][nn], 0, 0, 0);
                acc[m][nn] = __builtin_amdgcn_mfma_f32_16x16x32_bf16(rh[m], xl, acc[m][nn], 0, 0, 0);
                acc[m][nn] = __builtin_amdgcn_mfma_f32_16x16x32_bf16(rl[m], xh, acc[m][nn], 0, 0, 0);
            }
        }
        __syncthreads();
    }

    float* pb = partials + (size_t)s * (KCL * D);
    #pragma unroll
    for (int m = 0; m < 2; ++m)
        #pragma unroll
        for (int nn = 0; nn < 8; ++nn)
            #pragma unroll
            for (int q = 0; q < 4; ++q) {
                int cl = w * 32 + m * 16 + g * 4 + q;
                pb[(size_t)cl * D + dbase + nn * 16 + fr] = acc[m][nn][q];
            }
}

// ---------------- reduce: mu = (sum_s partials[s]) / cluster_r ; emit hi/lo bf16 ----------------
__global__ __launch_bounds__(256) void reduce_kernel(
    const float* __restrict__ partials, const float* __restrict__ cluster_r,
    float* __restrict__ mu_out, unsigned short* __restrict__ mh, unsigned short* __restrict__ ml,
    int gsplit)
{
    int idx = blockIdx.x * 256 + threadIdx.x;   // 0..65535
    float s = 0.f;
    for (int g = 0; g < gsplit; ++g) s += partials[(size_t)g * (KCL * D) + idx];
    int c = idx >> 9;                            // / D
    float m = s / cluster_r[c];
    mu_out[idx] = m;
    unsigned short h = f2bf(m);
    float hf = bf2f(h);
    mh[idx] = h;
    ml[idx] = f2bf(m - hf);
}

extern "C" void kernel_launch(void* const* d_in, const int* in_sizes, int n_in,
                              void* d_out, int out_size, void* d_ws, size_t ws_size,
                              hipStream_t stream)
{
    const float* x   = (const float*)d_in[0];
    const float* mu0 = (const float*)d_in[1];
    const int n = in_sizes[0] / D;   // 100000

    const int chunk   = ((n + SPLIT * 32 - 1) / (SPLIT * 32)) * 32;  // 800
    const int npad    = SPLIT * chunk;                                // 102400
    const int ablocks = (n + 127) / 128;                              // 782
    const int KT      = npad / 64;                                    // 1600

    char* ws = (char*)d_ws;
    size_t off = 0;
    auto alloc = [&](size_t bytes) { size_t cur = off; off += (bytes + 255) & ~(size_t)255; return cur; };
    float*          inv_norm = (float*)(ws + alloc((size_t)n * 4));
    float*          normp    = (float*)(ws + alloc((size_t)4 * n * 4));
    unsigned*       r_tp     = (unsigned*)(ws + alloc((size_t)KCL * npad * 4));
    unsigned*       xT_p     = (unsigned*)(ws + alloc((size_t)D * npad * 4));
    float*          parts    = (float*)(ws + alloc((size_t)SPLIT * KCL * D * 4));
    float*          cr       = (float*)(ws + alloc(512));
    float*          mu_a     = (float*)(ws + alloc((size_t)KCL * D * 4));
    unsigned short* muh      = (unsigned short*)(ws + alloc((size_t)KCL * D * 2));
    unsigned short* mul      = (unsigned short*)(ws + alloc((size_t)KCL * D * 2));

    float* mu_final = (float*)d_out;            // first 128*512 floats
    float* r_final  = (float*)d_out + KCL * D;  // then n*128 floats

    conv_xT_kernel<<<dim3(KT, 4), 256, 0, stream>>>(x, xT_p, normp, n, npad);
    norm_fin_kernel<<<dim3((n + 255) / 256), 256, 0, stream>>>(normp, inv_norm, n);
    conv_mu_kernel<<<dim3((KCL * D) / 1024), 256, 0, stream>>>(mu0, muh, mul);
    {
        int k0 = ablocks * 128;
        int cnt = npad - k0;
        int tot = KCL * cnt;
        if (tot > 0)
            pad_r_kernel<<<dim3((tot + 255) / 256), 256, 0, stream>>>(r_tp, npad, k0);
    }

    float* mu_tgt[3] = {mu_a, mu_a, mu_final};
    for (int it = 0; it < 3; ++it) {
        hipMemsetAsync(cr, 0, 512, stream);
        passA_mfma_kernel<false><<<dim3(ablocks), 256, 0, stream>>>(
            x, muh, mul, inv_norm, nullptr, r_tp, cr, n, npad);
        passB_mfma_kernel<<<dim3(4, SPLIT), 256, 0, stream>>>(r_tp, xT_p, parts, npad, chunk);
        reduce_kernel<<<dim3((KCL * D) / 256), 256, 0, stream>>>(parts, cr, mu_tgt[it], muh, mul, SPLIT);
    }
    passA_mfma_kernel<true><<<dim3(ablocks), 256, 0, stream>>>(
        x, muh, mul, inv_norm, r_final, nullptr, nullptr, n, npad);
}

// Round 8
// 1057.268 us; speedup vs baseline: 1.3140x; 1.3140x over previous
//
#include <hip/hip_runtime.h>
#include <math.h>

constexpr int D = 512;        // embedding dim
constexpr int KCL = 128;      // clusters
constexpr float BETA_C = 5.0f;
constexpr int SPLIT = 128;    // split-K groups for pass B

typedef __attribute__((ext_vector_type(8))) short short8;
typedef __attribute__((ext_vector_type(4))) float f32x4;

typedef const __attribute__((address_space(1))) unsigned int* gptr_t;
typedef __attribute__((address_space(3))) unsigned int* sptr_t;

static __device__ __forceinline__ unsigned short f2bf(float f) {
    unsigned u = __builtin_bit_cast(unsigned, f);
    unsigned r = (u + 0x7FFFu + ((u >> 16) & 1u)) >> 16;
    return (unsigned short)r;
}
static __device__ __forceinline__ float bf2f(unsigned short h) {
    unsigned u = ((unsigned)h) << 16;
    return __builtin_bit_cast(float, u);
}
static __device__ __forceinline__ unsigned pack_split(float v) {
    unsigned short h = f2bf(v);
    float hf = bf2f(h);
    unsigned short lo = f2bf(v - hf);
    return (unsigned)h | ((unsigned)lo << 16);
}
// unpack 8 packed u32 (hi | lo<<16) -> hi/lo bf16 frags
static __device__ __forceinline__ void unpack8(uint4 a, uint4 b, short8& hi, short8& lo) {
    union { unsigned u[4]; short8 s8; } H, L;
    H.u[0] = (a.x & 0xFFFFu) | (a.y << 16);
    H.u[1] = (a.z & 0xFFFFu) | (a.w << 16);
    H.u[2] = (b.x & 0xFFFFu) | (b.y << 16);
    H.u[3] = (b.z & 0xFFFFu) | (b.w << 16);
    L.u[0] = (a.x >> 16) | (a.y & 0xFFFF0000u);
    L.u[1] = (a.z >> 16) | (a.w & 0xFFFF0000u);
    L.u[2] = (b.x >> 16) | (b.y & 0xFFFF0000u);
    L.u[3] = (b.z >> 16) | (b.w & 0xFFFF0000u);
    hi = H.s8; lo = L.s8;
}

// fragment-major index for A/R-style tiles (128 rows x 32 k), u32 elements:
//   f(r,k) = (r>>5)*1024 + ((k>>2)&1)*512 + ((r>>4)&1)*256 + ((k>>3)*16 + (r&15))*4 + (k&3)

// ---------------- conv_xpA: x -> packed-limb tiles in A-fragment-major order ----------------
// xpA[tile_r][kt][4096 u32]; tile_r = n/128 tile, kt = d/32 tile.
__global__ __launch_bounds__(256) void conv_xpA_kernel(const float* __restrict__ x,
        unsigned* __restrict__ xpA, int n)
{
    __shared__ float tileA[128 * 36];
    const int t  = threadIdx.x;
    const int tr = blockIdx.x;
    const int kt = blockIdx.y;

    #pragma unroll
    for (int u = 0; u < 4; ++u) {
        int c   = t + u * 256;          // 0..1023 chunks of 4 floats
        int row = c >> 3;
        int c4  = (c & 7) << 2;
        int gr  = min(tr * 128 + row, n - 1);
        float4 v = *reinterpret_cast<const float4*>(x + (size_t)gr * D + kt * 32 + c4);
        *reinterpret_cast<float4*>(&tileA[row * 36 + c4]) = v;
    }
    __syncthreads();

    unsigned* dst = xpA + ((size_t)tr * 16 + kt) * 4096;
    #pragma unroll
    for (int u = 0; u < 4; ++u) {
        int q = t + u * 256;            // uint4 index 0..1023
        int w = q >> 8, h = (q >> 7) & 1, m = (q >> 6) & 1, l = q & 63;
        int row = w * 32 + m * 16 + (l & 15);
        int k   = (l >> 4) * 8 + h * 4;
        float4 v = *reinterpret_cast<const float4*>(&tileA[row * 36 + k]);
        uint4 o = make_uint4(pack_split(v.x), pack_split(v.y), pack_split(v.z), pack_split(v.w));
        *reinterpret_cast<uint4*>(dst + (size_t)q * 4) = o;
    }
}

// ---------------- conv_xT: x -> packed-limb tiles in B-fragment-major order + norm partials ----
// xt[dt][n_tile][4096 u32]; block = (n-chunk of 64, d-tile of 128) -> 2 n_tiles.
__global__ __launch_bounds__(256) void conv_xT_kernel(const float* __restrict__ x,
        unsigned* __restrict__ xt, float* __restrict__ normp, int n, int nTiles)
{
    __shared__ float tile[64 * 132];
    const int t  = threadIdx.x;
    const int nc = blockIdx.x;
    const int dt = blockIdx.y;

    #pragma unroll
    for (int u = 0; u < 8; ++u) {
        int f   = t + u * 256;
        int row = f >> 5;
        int c4  = (f & 31) << 2;
        int gk  = nc * 64 + row;
        float4 v = make_float4(0.f, 0.f, 0.f, 0.f);
        if (gk < n) v = *reinterpret_cast<const float4*>(x + (size_t)gk * D + dt * 128 + c4);
        *reinterpret_cast<float4*>(&tile[row * 132 + c4]) = v;
    }
    __syncthreads();

    {   // norm partials: 4 lanes per row, 32 d each
        int rowl = t >> 2, part = t & 3;
        int gk = nc * 64 + rowl;
        float s = 0.f;
        #pragma unroll
        for (int i = 0; i < 32; ++i) {
            float v = tile[rowl * 132 + part * 32 + i];
            s += v * v;
        }
        s += __shfl_xor(s, 1, 64);
        s += __shfl_xor(s, 2, 64);
        if (part == 0 && gk < n) normp[(size_t)dt * n + gk] = s;
    }

    #pragma unroll
    for (int u = 0; u < 8; ++u) {
        int q = t + u * 256;            // uint4 index within 2-tile region
        int ntloc = q >> 10;
        int qq = q & 1023;
        int nn = qq >> 7, h = (qq >> 6) & 1, l = qq & 63;
        int dr = nn * 16 + (l & 15);
        int kn = (l >> 4) * 8 + h * 4;
        uint4 o;
        o.x = pack_split(tile[(ntloc * 32 + kn + 0) * 132 + dr]);
        o.y = pack_split(tile[(ntloc * 32 + kn + 1) * 132 + dr]);
        o.z = pack_split(tile[(ntloc * 32 + kn + 2) * 132 + dr]);
        o.w = pack_split(tile[(ntloc * 32 + kn + 3) * 132 + dr]);
        *reinterpret_cast<uint4*>(xt + ((size_t)dt * nTiles + nc * 2 + ntloc) * 4096 + (size_t)qq * 4) = o;
    }
}

__global__ __launch_bounds__(256) void norm_fin_kernel(const float* __restrict__ normp,
        float* __restrict__ inv_norm, int n)
{
    int i = blockIdx.x * 256 + threadIdx.x;
    if (i < n)
        inv_norm[i] = 1.0f / sqrtf(normp[i] + normp[(size_t)n + i] +
                                   normp[2 * (size_t)n + i] + normp[3 * (size_t)n + i]);
}

// ---------------- conversion: mu fp32 -> hi/lo bf16 planes ----------------
__global__ __launch_bounds__(256) void conv_mu_kernel(const float* __restrict__ mu,
        unsigned short* __restrict__ mh, unsigned short* __restrict__ ml)
{
    int i = blockIdx.x * 256 + threadIdx.x;
    float4 v = reinterpret_cast<const float4*>(mu)[i];
    ushort4 h, l;
    float hf;
    h.x = f2bf(v.x); hf = bf2f(h.x); l.x = f2bf(v.x - hf);
    h.y = f2bf(v.y); hf = bf2f(h.y); l.y = f2bf(v.y - hf);
    h.z = f2bf(v.z); hf = bf2f(h.z); l.z = f2bf(v.z - hf);
    h.w = f2bf(v.w); hf = bf2f(h.w); l.w = f2bf(v.w - hf);
    reinterpret_cast<ushort4*>(mh)[i] = h;
    reinterpret_cast<ushort4*>(ml)[i] = l;
}

// ---------------- zero tail tiles of r_t ----------------
__global__ __launch_bounds__(256) void pad_r_kernel(unsigned* __restrict__ rt, size_t base, int cnt)
{
    int idx = blockIdx.x * 256 + threadIdx.x;
    if (idx < cnt) rt[base + idx] = 0u;
}

// ---------------- pass A (MFMA): r = softmax(beta * s_i * (x @ mu^T)) ----------------
// A from xpA (fragment-major packed limbs, linear staging); B from mu hi/lo planes staged
// fragment-major. FIN=false: writes r' packed limbs in R-fragment-major tiles + cluster_r.
template<bool FIN>
__global__ __launch_bounds__(256) void passA_mfma_kernel(
    const unsigned* __restrict__ xpA,
    const unsigned short* __restrict__ mh, const unsigned short* __restrict__ ml,
    const float* __restrict__ inv_norm, float* __restrict__ r_out,
    unsigned* __restrict__ r_tp, float* __restrict__ cluster_r, int n)
{
    __shared__ __align__(16) unsigned ldsA[4096];
    __shared__ __align__(16) unsigned short bhs[4096];
    __shared__ __align__(16) unsigned short bls[4096];
    __shared__ float part[512];

    const int t  = threadIdx.x;
    const int w  = t >> 6;
    const int l  = t & 63;
    const int fr = l & 15;
    const int g  = l >> 4;
    const int rowBase = blockIdx.x * 128;

    f32x4 acc[2][8];
    #pragma unroll
    for (int m = 0; m < 2; ++m)
        #pragma unroll
        for (int nn = 0; nn < 8; ++nn) acc[m][nn] = (f32x4){0.f, 0.f, 0.f, 0.f};

    const unsigned* srcA = xpA + (size_t)blockIdx.x * 65536 + t * 4;
    const unsigned short* pbh[2];
    const unsigned short* pbl[2];
    #pragma unroll
    for (int u = 0; u < 2; ++u) {
        int cc  = t + u * 256;          // 0..511 chunks of 8 ushorts
        int nn2 = cc >> 6, gg = (cc >> 4) & 3, fr2 = cc & 15;
        pbh[u] = mh + (nn2 * 16 + fr2) * D + gg * 8;
        pbl[u] = ml + (nn2 * 16 + fr2) * D + gg * 8;
    }

    for (int kt = 0; kt < 16; ++kt) {
        #pragma unroll
        for (int u = 0; u < 4; ++u)
            __builtin_amdgcn_global_load_lds((gptr_t)(srcA + u * 1024),
                                             (sptr_t)&ldsA[(t + u * 256) * 4], 16, 0, 0);
        #pragma unroll
        for (int u = 0; u < 2; ++u) {
            __builtin_amdgcn_global_load_lds((gptr_t)pbh[u], (sptr_t)&bhs[(t + u * 256) * 8], 16, 0, 0);
            __builtin_amdgcn_global_load_lds((gptr_t)pbl[u], (sptr_t)&bls[(t + u * 256) * 8], 16, 0, 0);
            pbh[u] += 32; pbl[u] += 32;
        }
        srcA += 4096;
        __syncthreads();

        short8 ah[2], al[2];
        #pragma unroll
        for (int m = 0; m < 2; ++m) {
            uint4 a0 = *reinterpret_cast<const uint4*>(&ldsA[w * 1024 +       m * 256 + l * 4]);
            uint4 a1 = *reinterpret_cast<const uint4*>(&ldsA[w * 1024 + 512 + m * 256 + l * 4]);
            unpack8(a0, a1, ah[m], al[m]);
        }
        #pragma unroll
        for (int nn = 0; nn < 8; ++nn) {
            short8 bhv = *reinterpret_cast<const short8*>(&bhs[nn * 512 + l * 8]);
            short8 blv = *reinterpret_cast<const short8*>(&bls[nn * 512 + l * 8]);
            acc[0][nn] = __builtin_amdgcn_mfma_f32_16x16x32_bf16(ah[0], bhv, acc[0][nn], 0, 0, 0);
            acc[1][nn] = __builtin_amdgcn_mfma_f32_16x16x32_bf16(ah[1], bhv, acc[1][nn], 0, 0, 0);
            acc[0][nn] = __builtin_amdgcn_mfma_f32_16x16x32_bf16(ah[0], blv, acc[0][nn], 0, 0, 0);
            acc[1][nn] = __builtin_amdgcn_mfma_f32_16x16x32_bf16(ah[1], blv, acc[1][nn], 0, 0, 0);
            acc[0][nn] = __builtin_amdgcn_mfma_f32_16x16x32_bf16(al[0], bhv, acc[0][nn], 0, 0, 0);
            acc[1][nn] = __builtin_amdgcn_mfma_f32_16x16x32_bf16(al[1], bhv, acc[1][nn], 0, 0, 0);
        }
        __syncthreads();
    }

    // -------- softmax + output --------
    float csum[8];
    #pragma unroll
    for (int nn = 0; nn < 8; ++nn) csum[nn] = 0.f;

    #pragma unroll
    for (int m = 0; m < 2; ++m) {
        unsigned wv[8][4];
        #pragma unroll
        for (int rr = 0; rr < 4; ++rr) {
            int row = rowBase + w * 32 + m * 16 + g * 4 + rr;
            bool valid = row < n;
            float sv = inv_norm[min(row, n - 1)];
            float bs = BETA_C * sv;
            float lg[8];
            float mx = -3.0e38f;
            #pragma unroll
            for (int nn = 0; nn < 8; ++nn) { lg[nn] = bs * acc[m][nn][rr]; mx = fmaxf(mx, lg[nn]); }
            #pragma unroll
            for (int sh = 1; sh < 16; sh <<= 1) mx = fmaxf(mx, __shfl_xor(mx, sh, 64));
            float e[8];
            float sum = 0.f;
            #pragma unroll
            for (int nn = 0; nn < 8; ++nn) { e[nn] = __expf(lg[nn] - mx); sum += e[nn]; }
            #pragma unroll
            for (int sh = 1; sh < 16; sh <<= 1) sum += __shfl_xor(sum, sh, 64);
            float rinv = 1.0f / sum;

            if (FIN) {
                if (valid) {
                    float* ro = r_out + (size_t)row * KCL + fr;
                    #pragma unroll
                    for (int nn = 0; nn < 8; ++nn) ro[nn * 16] = e[nn] * rinv;
                }
            } else {
                #pragma unroll
                for (int nn = 0; nn < 8; ++nn) {
                    unsigned pv = 0u;
                    if (valid) {
                        float rv = e[nn] * rinv;
                        csum[nn] += rv;
                        pv = pack_split(rv * sv);     // r' = r * s_i, packed limbs
                    }
                    wv[nn][rr] = pv;
                }
            }
        }
        if (!FIN) {
            // fragment-major tile write: tile nt = blockIdx.x*4 + w covers n rows [nt*32, nt*32+32)
            uint4* tb = reinterpret_cast<uint4*>(r_tp) + (size_t)(blockIdx.x * 4 + w) * 1024;
            #pragma unroll
            for (int nn = 0; nn < 8; ++nn) {
                int idx = (nn >> 1) * 256 + (g & 1) * 128 + (nn & 1) * 64
                        + (m * 2 + (g >> 1)) * 16 + fr;
                tb[idx] = make_uint4(wv[nn][0], wv[nn][1], wv[nn][2], wv[nn][3]);
            }
        }
    }

    if (!FIN) {
        #pragma unroll
        for (int nn = 0; nn < 8; ++nn) {
            csum[nn] += __shfl_xor(csum[nn], 16, 64);
            csum[nn] += __shfl_xor(csum[nn], 32, 64);
        }
        if (l < 16) {
            #pragma unroll
            for (int nn = 0; nn < 8; ++nn) part[w * 128 + nn * 16 + l] = csum[nn];
        }
        __syncthreads();
        if (t < 128) {
            atomicAdd(&cluster_r[t], part[t] + part[128 + t] + part[256 + t] + part[384 + t]);
        }
    }
}

// ---------------- pass B (MFMA): partials[s] = r' @ x over a tile range ----------------
__global__ __launch_bounds__(256) void passB_mfma_kernel(
    const unsigned* __restrict__ rt, const unsigned* __restrict__ xt,
    float* __restrict__ partials, int nTiles, int tilesPerSplit)
{
    __shared__ __align__(16) unsigned ldsR[4096];
    __shared__ __align__(16) unsigned ldsX[4096];

    const int t  = threadIdx.x;
    const int w  = t >> 6;
    const int l  = t & 63;
    const int fr = l & 15;
    const int g  = l >> 4;
    const int dt = blockIdx.x;
    const int s  = blockIdx.y;
    const int nt0 = s * tilesPerSplit;

    f32x4 acc[2][8];
    #pragma unroll
    for (int m = 0; m < 2; ++m)
        #pragma unroll
        for (int nn = 0; nn < 8; ++nn) acc[m][nn] = (f32x4){0.f, 0.f, 0.f, 0.f};

    const unsigned* srcR = rt + (size_t)nt0 * 4096 + t * 4;
    const unsigned* srcX = xt + ((size_t)dt * nTiles + nt0) * 4096 + t * 4;

    for (int it = 0; it < tilesPerSplit; ++it) {
        #pragma unroll
        for (int u = 0; u < 4; ++u) {
            __builtin_amdgcn_global_load_lds((gptr_t)(srcR + u * 1024),
                                             (sptr_t)&ldsR[(t + u * 256) * 4], 16, 0, 0);
            __builtin_amdgcn_global_load_lds((gptr_t)(srcX + u * 1024),
                                             (sptr_t)&ldsX[(t + u * 256) * 4], 16, 0, 0);
        }
        srcR += 4096; srcX += 4096;
        __syncthreads();

        short8 rh[2], rl[2];
        #pragma unroll
        for (int m = 0; m < 2; ++m) {
            uint4 a0 = *reinterpret_cast<const uint4*>(&ldsR[w * 1024 +       m * 256 + l * 4]);
            uint4 a1 = *reinterpret_cast<const uint4*>(&ldsR[w * 1024 + 512 + m * 256 + l * 4]);
            unpack8(a0, a1, rh[m], rl[m]);
        }
        #pragma unroll
        for (int nn = 0; nn < 8; ++nn) {
            uint4 b0 = *reinterpret_cast<const uint4*>(&ldsX[nn * 512 +       l * 4]);
            uint4 b1 = *reinterpret_cast<const uint4*>(&ldsX[nn * 512 + 256 + l * 4]);
            short8 xhv, xlv;
            unpack8(b0, b1, xhv, xlv);
            #pragma unroll
            for (int m = 0; m < 2; ++m) {
                acc[m][nn] = __builtin_amdgcn_mfma_f32_16x16x32_bf16(rh[m], xhv, acc[m][nn], 0, 0, 0);
                acc[m][nn] = __builtin_amdgcn_mfma_f32_16x16x32_bf16(rh[m], xlv, acc[m][nn], 0, 0, 0);
                acc[m][nn] = __builtin_amdgcn_mfma_f32_16x16x32_bf16(rl[m], xhv, acc[m][nn], 0, 0, 0);
            }
        }
        __syncthreads();
    }

    float* pb = partials + (size_t)s * (KCL * D);
    #pragma unroll
    for (int m = 0; m < 2; ++m)
        #pragma unroll
        for (int nn = 0; nn < 8; ++nn)
            #pragma unroll
            for (int q = 0; q < 4; ++q) {
                int cl = w * 32 + m * 16 + g * 4 + q;
                pb[(size_t)cl * D + dt * 128 + nn * 16 + fr] = acc[m][nn][q];
            }
}

// ---------------- reduce: mu = (sum_s partials[s]) / cluster_r ; emit hi/lo bf16 ----------------
__global__ __launch_bounds__(256) void reduce_kernel(
    const float* __restrict__ partials, const float* __restrict__ cluster_r,
    float* __restrict__ mu_out, unsigned short* __restrict__ mh, unsigned short* __restrict__ ml,
    int gsplit)
{
    int idx = blockIdx.x * 256 + threadIdx.x;   // 0..65535
    float s = 0.f;
    for (int g = 0; g < gsplit; ++g) s += partials[(size_t)g * (KCL * D) + idx];
    int c = idx >> 9;                            // / D
    float m = s / cluster_r[c];
    mu_out[idx] = m;
    unsigned short h = f2bf(m);
    float hf = bf2f(h);
    mh[idx] = h;
    ml[idx] = f2bf(m - hf);
}

extern "C" void kernel_launch(void* const* d_in, const int* in_sizes, int n_in,
                              void* d_out, int out_size, void* d_ws, size_t ws_size,
                              hipStream_t stream)
{
    const float* x   = (const float*)d_in[0];
    const float* mu0 = (const float*)d_in[1];
    const int n = in_sizes[0] / D;   // 100000

    const int chunk   = ((n + SPLIT * 32 - 1) / (SPLIT * 32)) * 32;  // 800
    const int npad    = SPLIT * chunk;                                // 102400
    const int ablocks = (n + 127) / 128;                              // 782
    const int nTiles  = npad / 32;                                    // 3200
    const int tps     = chunk / 32;                                   // 25

    char* ws = (char*)d_ws;
    size_t off = 0;
    auto alloc = [&](size_t bytes) { size_t cur = off; off += (bytes + 255) & ~(size_t)255; return cur; };
    float*          inv_norm = (float*)(ws + alloc((size_t)n * 4));
    float*          normp    = (float*)(ws + alloc((size_t)4 * n * 4));
    unsigned*       r_tp     = (unsigned*)(ws + alloc((size_t)nTiles * 4096 * 4));
    unsigned*       xT_p     = (unsigned*)(ws + alloc((size_t)4 * nTiles * 4096 * 4));
    unsigned*       xpA      = (unsigned*)(ws + alloc((size_t)ablocks * 16 * 4096 * 4));
    float*          parts    = (float*)(ws + alloc((size_t)SPLIT * KCL * D * 4));
    float*          cr       = (float*)(ws + alloc(512));
    float*          mu_a     = (float*)(ws + alloc((size_t)KCL * D * 4));
    unsigned short* muh      = (unsigned short*)(ws + alloc((size_t)KCL * D * 2));
    unsigned short* mul      = (unsigned short*)(ws + alloc((size_t)KCL * D * 2));

    float* mu_final = (float*)d_out;            // first 128*512 floats
    float* r_final  = (float*)d_out + KCL * D;  // then n*128 floats

    conv_xpA_kernel<<<dim3(ablocks, 16), 256, 0, stream>>>(x, xpA, n);
    conv_xT_kernel<<<dim3(npad / 64, 4), 256, 0, stream>>>(x, xT_p, normp, n, nTiles);
    norm_fin_kernel<<<dim3((n + 255) / 256), 256, 0, stream>>>(normp, inv_norm, n);
    conv_mu_kernel<<<dim3((KCL * D) / 1024), 256, 0, stream>>>(mu0, muh, mul);
    {
        size_t base = (size_t)ablocks * 4 * 4096;
        long long cnt = (long long)nTiles * 4096 - (long long)base;
        if (cnt > 0)
            pad_r_kernel<<<dim3((int)((cnt + 255) / 256)), 256, 0, stream>>>(r_tp, base, (int)cnt);
    }

    float* mu_tgt[3] = {mu_a, mu_a, mu_final};
    for (int it = 0; it < 3; ++it) {
        hipMemsetAsync(cr, 0, 512, stream);
        passA_mfma_kernel<false><<<dim3(ablocks), 256, 0, stream>>>(
            xpA, muh, mul, inv_norm, nullptr, r_tp, cr, n);
        passB_mfma_kernel<<<dim3(4, SPLIT), 256, 0, stream>>>(r_tp, xT_p, parts, nTiles, tps);
        reduce_kernel<<<dim3((KCL * D) / 256), 256, 0, stream>>>(parts, cr, mu_tgt[it], muh, mul, SPLIT);
    }
    passA_mfma_kernel<true><<<dim3(ablocks), 256, 0, stream>>>(
        xpA, muh, mul, inv_norm, r_final, nullptr, nullptr, n);
}